// Round 5
// baseline (474.882 us; speedup 1.0000x reference)
//
#include <hip/hip_runtime.h>
#include <stdint.h>

// SpikingNeuralNetwork: B=32, S=4096, D=512, H=256, OUT=128
// Fused single-kernel producer->consumer pipeline. Cross-XCD coherence:
// producer publishes currents with relaxed AGENT-scope dword stores (sc1
// write-through -> device coherence point) + flag counters; consumer DMAs
// them with plain global_load_lds (consumer XCD L2 is invalidated at
// dispatch start and never touches cur before the flag, so plain reads are
// fresh — the same mechanism that made the 2-kernel round-0 version correct,
// gated by flags instead of a kernel boundary). Zero cache-maintenance ops.
//
// Round-4 post-mortem: producers ~60-65 us at ~50% occupancy, then ~127 us
// consumer-only tail. Cause: 64 scalar coherent loads per chunk exceed the
// 6-bit vmcnt counter (max 63) -> compiler emits s_waitcnt vmcnt(0) per
// chunk -> one full ~700cy latency exposed per chunk. Fix: float4-packed cur
// (16 x 16B global_load_lds per chunk, manual s_waitcnt vmcnt(16)) so the
// next chunk's DMA stays in flight under the current chunk's scan.
//
// Producers (blocks 4..1027, 1 float4-row f = blockIdx-4, s-rows 4f..4f+3):
//   batch-mean of x + GEMV projection (arithmetic byte-identical to the
//   verified absmax-0.0 kernels). Store acc2[0..3] as the packed float4
//   cur4[f][h] via 4 relaxed agent dword stores; __syncthreads (s_waitcnt
//   vmcnt(0) -> stores at coherence point); relaxed agent atomicAdd on
//   ctr[f>>6] (16 counters, one per 4-chunk group, goal 64).
// Consumers (blocks 0..3, 1 wave): LIF scan, one neuron chain per lane.
//   Per chunk: poll (at 4-chunk boundaries only), issue 16 global_load_lds
//   into LDS double buffer, vmcnt(16) waits only the PREVIOUS chunk's DMAs,
//   LDS->reg block copy (compiler-tracked lgkmcnt; can't hoist past the
//   "memory" asm since LDS reads are compiler-visible memory ops),
//   sched_barrier(0) pins order, then 64 serial LIF steps.
// Residency: 1028 blocks, VGPR~104 & LDS 33 KB -> 4 blocks/CU; consumers are
//   blockIdx 0..3 (first dispatch wave, co-resident from t=0). Deadlock-free:
//   producers never wait.

#define S_LEN 4096
#define D_DIM 512
#define H_DIM 256
#define O_DIM 128
#define B_SZ  32

#define NPROD 1024              // producer blocks (1 float4-row each)
#define NCONS 4                 // consumer blocks (64 neurons each), blockIdx 0..3
#define CH    64                // scan steps per chunk
#define NCH   (S_LEN / CH)      // 64 chunks
#define ROWS  (CH / 4)          // 16 float4-rows per chunk
#define NGRP  16                // progress counters (4 chunks / group)
#define GOAL  64u               // float4-rows per group

typedef const __attribute__((address_space(1))) void  glob_void;
typedef       __attribute__((address_space(3))) void  lds_void;

// One LIF step, fused form (bit-exact to reference):
#define LIF_STEP(IC) {                          \
    float ict = sp2 ? 0.f : (IC);               \
    float tt  = fmaf(0.95f, u, ict);            \
    u   = sp1 ? 0.f : tt;                       \
    bool sp = (u >= 1.0f);                      \
    cnt += sp ? 1 : 0;                          \
    sp2 = sp1; sp1 = sp; }

#define ACC4(A, V) { A.x += V.x; A.y += V.y; A.z += V.z; A.w += V.w; }

__global__ __launch_bounds__(256, 2)
void snn_fused(const float4* __restrict__ x4,
               const float*  __restrict__ iw,
               const float*  __restrict__ hw,
               float*        __restrict__ cur,    // packed: [f][h] float4 = 4 MB
               uint32_t*     __restrict__ ctr,
               float*        __restrict__ out) {
    // LDS: consumer 2x16KB DMA double buffer + 256B counts; producer xm
    // (8 KB) overlays the front (disjoint block roles).
    __shared__ __attribute__((aligned(16))) char smem[2 * ROWS * 64 * 16 + 256];
    const int t = threadIdx.x;

    if (blockIdx.x >= NCONS) {
        // ------------------------- producer -------------------------
        float4* xm = (float4*)smem;            // [4][128] float4
        const int r2 = t >> 7;                 // 0..1: this thread's row pair
        const int d4 = t & 127;
        const int h  = t;
        const float inv = 1.0f / (float)B_SZ;
        const size_t bstr = (size_t)S_LEN * (D_DIM / 4);   // batch stride (float4)

        const int f  = (int)blockIdx.x - NCONS;  // float4-row 0..1023
        const int s0 = 4 * f;

        // Stage 1: batch-mean of rows s0+r2 and s0+r2+2 (ascending-b order,
        // identical accumulation sequence to the verified kernels).
        float4 a0 = make_float4(0.f, 0.f, 0.f, 0.f);
        float4 a1 = make_float4(0.f, 0.f, 0.f, 0.f);
        const float4* xb = x4 + (size_t)(s0 + r2) * (D_DIM / 4) + d4;
        for (int b = 0; b < B_SZ; b += 4) {
            const float4* p = xb + (size_t)b * bstr;
            float4 v00 = p[0],            v01 = p[2 * (D_DIM / 4)];
            float4 v10 = p[bstr],         v11 = p[bstr + 2 * (D_DIM / 4)];
            float4 v20 = p[2 * bstr],     v21 = p[2 * bstr + 2 * (D_DIM / 4)];
            float4 v30 = p[3 * bstr],     v31 = p[3 * bstr + 2 * (D_DIM / 4)];
            ACC4(a0, v00); ACC4(a0, v10); ACC4(a0, v20); ACC4(a0, v30);
            ACC4(a1, v01); ACC4(a1, v11); ACC4(a1, v21); ACC4(a1, v31);
        }
        a0.x *= inv; a0.y *= inv; a0.z *= inv; a0.w *= inv;
        a1.x *= inv; a1.y *= inv; a1.z *= inv; a1.w *= inv;
        xm[r2 * (D_DIM / 4) + d4]       = a0;   // row s0+r2
        xm[(r2 + 2) * (D_DIM / 4) + d4] = a1;   // row s0+r2+2
        __syncthreads();

        // Stage 2: currents[s0+r][h] = sum_d xm[r][d] * W_in[d][h]; thread = h.
        float acc2[4] = {0.f, 0.f, 0.f, 0.f};
        for (int d4i = 0; d4i < D_DIM / 4; ++d4i) {
            const int d = d4i * 4;
            float w0 = iw[(d + 0) * H_DIM + h];
            float w1 = iw[(d + 1) * H_DIM + h];
            float w2 = iw[(d + 2) * H_DIM + h];
            float w3 = iw[(d + 3) * H_DIM + h];
            #pragma unroll
            for (int r = 0; r < 4; ++r) {
                float4 xv = xm[r * (D_DIM / 4) + d4i];   // same-addr broadcast
                acc2[r] += xv.x * w0 + xv.y * w1 + xv.z * w2 + xv.w * w3;
            }
        }
        // Packed store cur4[f][h] = {s=4f..4f+3}: 4 relaxed agent dword
        // stores (sc1 write-through; same values/order as the verified
        // row-major version, only the address layout changed).
        {
            float* dst = cur + ((size_t)f * H_DIM + h) * 4;
            #pragma unroll
            for (int r = 0; r < 4; ++r)
                __hip_atomic_store(dst + r, acc2[r],
                                   __ATOMIC_RELAXED, __HIP_MEMORY_SCOPE_AGENT);
        }
        // Publish: barrier drains vmcnt(0) (all threads' stores at the
        // coherence point), then a relaxed device-scope counter bump.
        __syncthreads();
        if (t == 0)
            __hip_atomic_fetch_add(&ctr[f >> 6], 1u, __ATOMIC_RELAXED,
                                   __HIP_MEMORY_SCOPE_AGENT);
        return;
    }

    // ------------------------- consumer -------------------------
    if (t >= 64) return;                       // 1 wave per consumer block
    float4 (*lbuf)[ROWS * 64] = (float4 (*)[ROWS * 64])smem;
    float* cl = (float*)(smem + 2 * ROWS * 64 * 16);
    const int lane  = t;
    const int hbase = (int)blockIdx.x * 64;
    const float4* cur4 = (const float4*)cur;

    // Chunk c needs its 4-chunk group's 64 float4-rows published. Poll only
    // at group boundaries (16 polls total); the poll's compiler-emitted
    // vmcnt(0) drains the in-flight DMA, which was about to be waited anyway.
    auto wait_grp = [&](int c) {
        if ((c & 3) != 0) return;
        const int gi = c >> 2;
        if (lane == 0) {
            while (__hip_atomic_load(&ctr[gi], __ATOMIC_RELAXED,
                                     __HIP_MEMORY_SCOPE_AGENT) < GOAL)
                __builtin_amdgcn_s_sleep(8);
        }
    };
    // 16 x 16B DMA for chunk c into lbuf[c&1]; dest = uniform base + lane*16.
    auto stage = [&](int c) {
        #pragma unroll
        for (int r = 0; r < ROWS; ++r) {
            const float4* g = cur4 + (size_t)(c * ROWS + r) * H_DIM + hbase + lane;
            __builtin_amdgcn_global_load_lds((glob_void*)g,
                                             (lds_void*)&lbuf[c & 1][r * 64 + lane],
                                             16, 0, 0);
        }
    };

    float u = 0.f;
    int   cnt = 0;
    bool  sp1 = false, sp2 = false;

    wait_grp(0);
    stage(0);
    for (int c = 0; c < NCH; ++c) {
        if (c + 1 < NCH) {
            wait_grp(c + 1);
            stage(c + 1);
            // Wait chunk c's 16 oldest DMAs; chunk c+1's 16 stay in flight.
            asm volatile("s_waitcnt vmcnt(16)" ::: "memory");
        } else {
            asm volatile("s_waitcnt vmcnt(0)" ::: "memory");
        }
        __builtin_amdgcn_sched_barrier(0);
        const float4* lb = lbuf[c & 1];
        float4 v[ROWS];
        #pragma unroll
        for (int r = 0; r < ROWS; ++r) v[r] = lb[r * 64 + lane];
        __builtin_amdgcn_sched_barrier(0);     // keep reads out of the chain

        #pragma unroll
        for (int r = 0; r < ROWS; ++r) {
            LIF_STEP(v[r].x); LIF_STEP(v[r].y); LIF_STEP(v[r].z); LIF_STEP(v[r].w);
        }
    }

    // Epilogue: partial out_mean over this block's 64 neurons, atomic-combined.
    __syncthreads();
    cl[lane] = (float)cnt;
    __syncthreads();
    float a0 = 0.f, a1 = 0.f;
    #pragma unroll 8
    for (int k = 0; k < 64; ++k) {
        float c = cl[k];
        const float* w = hw + (size_t)(hbase + k) * O_DIM;
        a0 = fmaf(c, w[lane], a0);
        a1 = fmaf(c, w[lane + 64], a1);
    }
    a0 *= (1.0f / (float)S_LEN);
    a1 *= (1.0f / (float)S_LEN);
    for (int b = 0; b < B_SZ; ++b) {
        atomicAdd(out + b * O_DIM + lane,      a0);
        atomicAdd(out + b * O_DIM + lane + 64, a1);
    }
}

extern "C" void kernel_launch(void* const* d_in, const int* in_sizes, int n_in,
                              void* d_out, int out_size, void* d_ws, size_t ws_size,
                              hipStream_t stream) {
    const float4* x4 = (const float4*)d_in[0];       // [32,4096,512] f32
    const float*  iw = (const float*) d_in[1];       // [512,256] f32
    const float*  hw = (const float*) d_in[2];       // [256,128] f32
    float* out = (float*)d_out;                      // [32,128] f32
    float* cur = (float*)d_ws;                       // [1024][256] float4 = 4 MB
    uint32_t* ctr = (uint32_t*)((char*)d_ws + (size_t)4 * 1024 * 1024);

    (void)hipMemsetAsync(ctr, 0, NGRP * sizeof(uint32_t), stream);
    (void)hipMemsetAsync(out, 0, B_SZ * O_DIM * sizeof(float), stream);
    hipLaunchKernelGGL(snn_fused, dim3(NCONS + NPROD), dim3(256), 0, stream,
                       x4, iw, hw, cur, ctr, out);
}

// Round 6
// 472.600 us; speedup vs baseline: 1.0048x; 1.0048x over previous
//
#include <hip/hip_runtime.h>
#include <stdint.h>

// SpikingNeuralNetwork: B=32, S=4096, D=512, H=256, OUT=128
// Fused single-kernel producer->consumer pipeline. Cross-XCD coherence:
// producer publishes currents with relaxed AGENT-scope stores (sc1
// write-through -> device coherence point) + flag counters; consumer DMAs
// them with plain global_load_lds into LDS (consumer's L2 never holds a
// stale copy of cur: it is only read after the flag).
//
// Round-5 post-mortem: VGPR_Count fell to 52 -> the consumer's 16xfloat4
// block-copy (needs 64 VGPR live) SPILLED to scratch inside the serial LIF
// chain, and the producer's 8-in-flight load batch was squeezed too — one
// regalloc decision slowed both phases (219us > R4's 192us). Also the 4B-
// stride-16B packed publish caused 4x partial-line write-through
// amplification (WRITE_SIZE 4.2->16.5MB).
// Fixes: (1) consumer uses a named-register rotation (p0/p1, prefetch depth
// 2, fully unrolled -> static indices, ~12 VGPR live); (2)
// __launch_bounds__(256,4) = 128 VGPR budget (4 waves/EU = 4 blocks/CU);
// (3) producer publishes via 2 x u64 atomic stores (8B/lane, halves the
// write amplification; bit-identical float values).
//
// Producers (blocks 4..1027, 1 float4-row f = blockIdx-4, s-rows 4f..4f+3):
//   batch-mean of x + GEMV projection (arithmetic byte-identical to the
//   verified absmax-0.0 kernels). Publish packed cur4[f][h] via 2 relaxed
//   agent u64 stores; __syncthreads (s_waitcnt vmcnt(0) -> stores at
//   coherence point); relaxed agent atomicAdd on ctr[f>>6] (16 counters,
//   one per 4-chunk group, goal 64).
// Consumers (blocks 0..3, 1 wave): LIF scan, one neuron chain per lane.
//   Per chunk: poll (4-chunk boundaries only), 16 x 16B global_load_lds into
//   LDS double buffer, manual s_waitcnt vmcnt(16) so next chunk's DMA stays
//   in flight under this chunk's scan; ds_read p0/p1 rotation feeds the
//   64 serial LIF steps.
// Residency: 1028 blocks, 33KB LDS & <=128 VGPR -> 4 blocks/CU; consumers
//   are blockIdx 0..3 (first dispatch wave). Deadlock-free: producers never
//   wait.

#define S_LEN 4096
#define D_DIM 512
#define H_DIM 256
#define O_DIM 128
#define B_SZ  32

#define NPROD 1024              // producer blocks (1 float4-row each)
#define NCONS 4                 // consumer blocks (64 neurons each), blockIdx 0..3
#define CH    64                // scan steps per chunk
#define NCH   (S_LEN / CH)      // 64 chunks
#define ROWS  (CH / 4)          // 16 float4-rows per chunk
#define NGRP  16                // progress counters (4 chunks / group)
#define GOAL  64u               // float4-rows per group

typedef const __attribute__((address_space(1))) void  glob_void;
typedef       __attribute__((address_space(3))) void  lds_void;

// One LIF step, fused form (bit-exact to reference):
#define LIF_STEP(IC) {                          \
    float ict = sp2 ? 0.f : (IC);               \
    float tt  = fmaf(0.95f, u, ict);            \
    u   = sp1 ? 0.f : tt;                       \
    bool sp = (u >= 1.0f);                      \
    cnt += sp ? 1 : 0;                          \
    sp2 = sp1; sp1 = sp; }

#define ACC4(A, V) { A.x += V.x; A.y += V.y; A.z += V.z; A.w += V.w; }

__global__ __launch_bounds__(256, 4)
void snn_fused(const float4* __restrict__ x4,
               const float*  __restrict__ iw,
               const float*  __restrict__ hw,
               float*        __restrict__ cur,    // packed: [f][h] float4 = 4 MB
               uint32_t*     __restrict__ ctr,
               float*        __restrict__ out) {
    // LDS: consumer 2x16KB DMA double buffer + 256B counts; producer xm
    // (8 KB) overlays the front (disjoint block roles).
    __shared__ __attribute__((aligned(16))) char smem[2 * ROWS * 64 * 16 + 256];
    const int t = threadIdx.x;

    if (blockIdx.x >= NCONS) {
        // ------------------------- producer -------------------------
        float4* xm = (float4*)smem;            // [4][128] float4
        const int r2 = t >> 7;                 // 0..1: this thread's row pair
        const int d4 = t & 127;
        const int h  = t;
        const float inv = 1.0f / (float)B_SZ;
        const size_t bstr = (size_t)S_LEN * (D_DIM / 4);   // batch stride (float4)

        const int f  = (int)blockIdx.x - NCONS;  // float4-row 0..1023
        const int s0 = 4 * f;

        // Stage 1: batch-mean of rows s0+r2 and s0+r2+2 (ascending-b order,
        // identical accumulation sequence to the verified kernels).
        float4 a0 = make_float4(0.f, 0.f, 0.f, 0.f);
        float4 a1 = make_float4(0.f, 0.f, 0.f, 0.f);
        const float4* xb = x4 + (size_t)(s0 + r2) * (D_DIM / 4) + d4;
        for (int b = 0; b < B_SZ; b += 4) {
            const float4* p = xb + (size_t)b * bstr;
            float4 v00 = p[0],            v01 = p[2 * (D_DIM / 4)];
            float4 v10 = p[bstr],         v11 = p[bstr + 2 * (D_DIM / 4)];
            float4 v20 = p[2 * bstr],     v21 = p[2 * bstr + 2 * (D_DIM / 4)];
            float4 v30 = p[3 * bstr],     v31 = p[3 * bstr + 2 * (D_DIM / 4)];
            ACC4(a0, v00); ACC4(a0, v10); ACC4(a0, v20); ACC4(a0, v30);
            ACC4(a1, v01); ACC4(a1, v11); ACC4(a1, v21); ACC4(a1, v31);
        }
        a0.x *= inv; a0.y *= inv; a0.z *= inv; a0.w *= inv;
        a1.x *= inv; a1.y *= inv; a1.z *= inv; a1.w *= inv;
        xm[r2 * (D_DIM / 4) + d4]       = a0;   // row s0+r2
        xm[(r2 + 2) * (D_DIM / 4) + d4] = a1;   // row s0+r2+2
        __syncthreads();

        // Stage 2: currents[s0+r][h] = sum_d xm[r][d] * W_in[d][h]; thread = h.
        float acc2[4] = {0.f, 0.f, 0.f, 0.f};
        for (int d4i = 0; d4i < D_DIM / 4; ++d4i) {
            const int d = d4i * 4;
            float w0 = iw[(d + 0) * H_DIM + h];
            float w1 = iw[(d + 1) * H_DIM + h];
            float w2 = iw[(d + 2) * H_DIM + h];
            float w3 = iw[(d + 3) * H_DIM + h];
            #pragma unroll
            for (int r = 0; r < 4; ++r) {
                float4 xv = xm[r * (D_DIM / 4) + d4i];   // same-addr broadcast
                acc2[r] += xv.x * w0 + xv.y * w1 + xv.z * w2 + xv.w * w3;
            }
        }
        // Packed publish cur4[f][h] = {s=4f..4f+3}: 2 relaxed agent u64
        // stores (sc1 write-through). Bit-identical float values; 8B/lane
        // halves partial-line write amplification vs 4x dword.
        {
            union { float fl[4]; unsigned long long ul[2]; } pk;
            pk.fl[0] = acc2[0]; pk.fl[1] = acc2[1];
            pk.fl[2] = acc2[2]; pk.fl[3] = acc2[3];
            unsigned long long* dst =
                (unsigned long long*)(cur + ((size_t)f * H_DIM + h) * 4);
            __hip_atomic_store(dst + 0, pk.ul[0],
                               __ATOMIC_RELAXED, __HIP_MEMORY_SCOPE_AGENT);
            __hip_atomic_store(dst + 1, pk.ul[1],
                               __ATOMIC_RELAXED, __HIP_MEMORY_SCOPE_AGENT);
        }
        // Publish: barrier drains vmcnt(0) (all threads' stores at the
        // coherence point), then a relaxed device-scope counter bump.
        __syncthreads();
        if (t == 0)
            __hip_atomic_fetch_add(&ctr[f >> 6], 1u, __ATOMIC_RELAXED,
                                   __HIP_MEMORY_SCOPE_AGENT);
        return;
    }

    // ------------------------- consumer -------------------------
    if (t >= 64) return;                       // 1 wave per consumer block
    float4 (*lbuf)[ROWS * 64] = (float4 (*)[ROWS * 64])smem;
    float* cl = (float*)(smem + 2 * ROWS * 64 * 16);
    const int lane  = t;
    const int hbase = (int)blockIdx.x * 64;
    const float4* cur4 = (const float4*)cur;

    // Chunk c needs its 4-chunk group's 64 float4-rows published. Poll only
    // at group boundaries (16 polls total).
    auto wait_grp = [&](int c) {
        if ((c & 3) != 0) return;
        const int gi = c >> 2;
        if (lane == 0) {
            while (__hip_atomic_load(&ctr[gi], __ATOMIC_RELAXED,
                                     __HIP_MEMORY_SCOPE_AGENT) < GOAL)
                __builtin_amdgcn_s_sleep(8);
        }
    };
    // 16 x 16B DMA for chunk c into lbuf[c&1]; dest = uniform base + lane*16.
    auto stage = [&](int c) {
        #pragma unroll
        for (int r = 0; r < ROWS; ++r) {
            const float4* g = cur4 + (size_t)(c * ROWS + r) * H_DIM + hbase + lane;
            __builtin_amdgcn_global_load_lds((glob_void*)g,
                                             (lds_void*)&lbuf[c & 1][r * 64 + lane],
                                             16, 0, 0);
        }
    };

    float u = 0.f;
    int   cnt = 0;
    bool  sp1 = false, sp2 = false;

    wait_grp(0);
    stage(0);
    for (int c = 0; c < NCH; ++c) {
        if (c + 1 < NCH) {
            wait_grp(c + 1);
            stage(c + 1);
            // Wait chunk c's 16 oldest DMAs; chunk c+1's 16 stay in flight.
            asm volatile("s_waitcnt vmcnt(16)" ::: "memory");
        } else {
            asm volatile("s_waitcnt vmcnt(0)" ::: "memory");
        }
        __builtin_amdgcn_sched_barrier(0);

        // Named-register rotation (static indices only — no spillable array):
        // prefetch depth 2 hides ds_read latency under ~2 scan iterations.
        const float4* lb = lbuf[c & 1];
        float4 p0 = lb[0 * 64 + lane];
        float4 p1 = lb[1 * 64 + lane];
        #pragma unroll
        for (int r = 0; r < ROWS; ++r) {
            float4 pc = p0;
            p0 = p1;
            if (r + 2 < ROWS) p1 = lb[(r + 2) * 64 + lane];
            LIF_STEP(pc.x); LIF_STEP(pc.y); LIF_STEP(pc.z); LIF_STEP(pc.w);
        }
    }

    // Epilogue: partial out_mean over this block's 64 neurons, atomic-combined.
    __syncthreads();
    cl[lane] = (float)cnt;
    __syncthreads();
    float a0 = 0.f, a1 = 0.f;
    #pragma unroll 8
    for (int k = 0; k < 64; ++k) {
        float c = cl[k];
        const float* w = hw + (size_t)(hbase + k) * O_DIM;
        a0 = fmaf(c, w[lane], a0);
        a1 = fmaf(c, w[lane + 64], a1);
    }
    a0 *= (1.0f / (float)S_LEN);
    a1 *= (1.0f / (float)S_LEN);
    for (int b = 0; b < B_SZ; ++b) {
        atomicAdd(out + b * O_DIM + lane,      a0);
        atomicAdd(out + b * O_DIM + lane + 64, a1);
    }
}

extern "C" void kernel_launch(void* const* d_in, const int* in_sizes, int n_in,
                              void* d_out, int out_size, void* d_ws, size_t ws_size,
                              hipStream_t stream) {
    const float4* x4 = (const float4*)d_in[0];       // [32,4096,512] f32
    const float*  iw = (const float*) d_in[1];       // [512,256] f32
    const float*  hw = (const float*) d_in[2];       // [256,128] f32
    float* out = (float*)d_out;                      // [32,128] f32
    float* cur = (float*)d_ws;                       // [1024][256] float4 = 4 MB
    uint32_t* ctr = (uint32_t*)((char*)d_ws + (size_t)4 * 1024 * 1024);

    (void)hipMemsetAsync(ctr, 0, NGRP * sizeof(uint32_t), stream);
    (void)hipMemsetAsync(out, 0, B_SZ * O_DIM * sizeof(float), stream);
    hipLaunchKernelGGL(snn_fused, dim3(NCONS + NPROD), dim3(256), 0, stream,
                       x4, iw, hw, cur, ctr, out);
}

// Round 7
// 468.291 us; speedup vs baseline: 1.0141x; 1.0092x over previous
//
#include <hip/hip_runtime.h>
#include <stdint.h>

// SpikingNeuralNetwork: B=32, S=4096, D=512, H=256, OUT=128
// TWO-KERNEL pipeline (un-fused).
//
// Round-6 post-mortem: the fused kernel has ONE register allocation shared
// by both roles. R4: consumer's v[16] block-copy forced VGPR=104 -> producer
// got 8-in-flight loads (192us). R5/R6: lean consumer -> allocator minimized
// to VGPR=52 -> producer loads serialized (218us). Also, all 1024 producer
// blocks are co-resident with equal work, so every chunk-group completes at
// ~the same instant: the intra-kernel producer->consumer overlap bought
// nothing. Un-fusing gives each phase its own regalloc, removes flags/polls/
// sc1 write-through (WRITE_SIZE 8.3 -> ~4.2 MB), and gives ground-truth
// per-phase timing (two dispatches).
//
// Kernel A (snn_produce, 1024 blocks x 256): block f computes s-rows
//   4f..4f+3: batch-mean of x over B (268 MB stream, 8 loads in flight) +
//   GEMV projection to H=256. Plain coalesced float4 store to packed
//   cur4[f][h] (16 B/lane, full 64B lines). Kernel-boundary coherence
//   (proven: round-0 passed absmax 0.0 with exactly this mechanism).
// Kernel B (snn_scan, 4 blocks x 64): LIF scan, one neuron chain per lane.
//   Per chunk: 16 x 16B global_load_lds into 2x16KB LDS double buffer;
//   manual s_waitcnt vmcnt(16) so chunk c+1's DMA stays in flight under
//   chunk c's scan; v[16] block copy (64 VGPR, no spill at
//   __launch_bounds__(64)); sched_barrier(0) pins copy/scan order.
// Mean/GEMV/LIF/epilogue arithmetic byte-identical to the verified
// absmax-0.0 kernels of rounds 0-6.

#define S_LEN 4096
#define D_DIM 512
#define H_DIM 256
#define O_DIM 128
#define B_SZ  32

#define NPROD 1024              // producer blocks (1 float4-row each)
#define CH    64                // scan steps per chunk
#define NCH   (S_LEN / CH)      // 64 chunks
#define ROWS  (CH / 4)          // 16 float4-rows per chunk

typedef const __attribute__((address_space(1))) void  glob_void;
typedef       __attribute__((address_space(3))) void  lds_void;

// One LIF step, fused form (bit-exact to reference):
#define LIF_STEP(IC) {                          \
    float ict = sp2 ? 0.f : (IC);               \
    float tt  = fmaf(0.95f, u, ict);            \
    u   = sp1 ? 0.f : tt;                       \
    bool sp = (u >= 1.0f);                      \
    cnt += sp ? 1 : 0;                          \
    sp2 = sp1; sp1 = sp; }

#define ACC4(A, V) { A.x += V.x; A.y += V.y; A.z += V.z; A.w += V.w; }

__global__ __launch_bounds__(256)
void snn_produce(const float4* __restrict__ x4,
                 const float*  __restrict__ iw,
                 float4*       __restrict__ cur4) {   // packed [f][h], 4 MB
    __shared__ float4 xm[4 * (D_DIM / 4)];   // 4 s-rows x 512 f32 = 8 KB
    const int t   = threadIdx.x;
    const int r2  = t >> 7;                  // 0..1: this thread's row pair
    const int d4  = t & 127;
    const int h   = t;
    const float inv = 1.0f / (float)B_SZ;
    const size_t bstr = (size_t)S_LEN * (D_DIM / 4);   // batch stride (float4)

    const int f  = (int)blockIdx.x;          // float4-row 0..1023
    const int s0 = 4 * f;

    // Stage 1: batch-mean of rows s0+r2 and s0+r2+2 (ascending-b order,
    // identical accumulation sequence to the verified kernels; 8 independent
    // loads in flight per thread).
    float4 a0 = make_float4(0.f, 0.f, 0.f, 0.f);
    float4 a1 = make_float4(0.f, 0.f, 0.f, 0.f);
    const float4* xb = x4 + (size_t)(s0 + r2) * (D_DIM / 4) + d4;
    for (int b = 0; b < B_SZ; b += 4) {
        const float4* p = xb + (size_t)b * bstr;
        float4 v00 = p[0],            v01 = p[2 * (D_DIM / 4)];
        float4 v10 = p[bstr],         v11 = p[bstr + 2 * (D_DIM / 4)];
        float4 v20 = p[2 * bstr],     v21 = p[2 * bstr + 2 * (D_DIM / 4)];
        float4 v30 = p[3 * bstr],     v31 = p[3 * bstr + 2 * (D_DIM / 4)];
        ACC4(a0, v00); ACC4(a0, v10); ACC4(a0, v20); ACC4(a0, v30);
        ACC4(a1, v01); ACC4(a1, v11); ACC4(a1, v21); ACC4(a1, v31);
    }
    a0.x *= inv; a0.y *= inv; a0.z *= inv; a0.w *= inv;
    a1.x *= inv; a1.y *= inv; a1.z *= inv; a1.w *= inv;
    xm[r2 * (D_DIM / 4) + d4]       = a0;    // row s0+r2
    xm[(r2 + 2) * (D_DIM / 4) + d4] = a1;    // row s0+r2+2
    __syncthreads();

    // Stage 2: currents[s0+r][h] = sum_d xm[r][d] * W_in[d][h]; thread = h.
    float acc2[4] = {0.f, 0.f, 0.f, 0.f};
    for (int d4i = 0; d4i < D_DIM / 4; ++d4i) {
        const int d = d4i * 4;
        float w0 = iw[(d + 0) * H_DIM + h];
        float w1 = iw[(d + 1) * H_DIM + h];
        float w2 = iw[(d + 2) * H_DIM + h];
        float w3 = iw[(d + 3) * H_DIM + h];
        #pragma unroll
        for (int r = 0; r < 4; ++r) {
            float4 xv = xm[r * (D_DIM / 4) + d4i];   // same-addr broadcast
            acc2[r] += xv.x * w0 + xv.y * w1 + xv.z * w2 + xv.w * w3;
        }
    }
    // Packed coalesced store: lane h contiguous -> 16 B/lane, full lines.
    cur4[(size_t)f * H_DIM + h] = make_float4(acc2[0], acc2[1], acc2[2], acc2[3]);
}

__global__ __launch_bounds__(64)
void snn_scan(const float4* __restrict__ cur4,
              const float*  __restrict__ hw,
              float*        __restrict__ out) {
    __shared__ __attribute__((aligned(16))) float4 lbuf[2][ROWS * 64];  // 2x16KB
    __shared__ float cl[64];
    const int lane  = threadIdx.x;           // one neuron chain per lane
    const int hbase = (int)blockIdx.x * 64;  // 4 blocks cover h=0..255

    // 16 x 16B DMA for chunk c into lbuf[c&1]; dest = uniform base + lane*16.
    auto stage = [&](int c) {
        #pragma unroll
        for (int r = 0; r < ROWS; ++r) {
            const float4* g = cur4 + (size_t)(c * ROWS + r) * H_DIM + hbase + lane;
            __builtin_amdgcn_global_load_lds((glob_void*)g,
                                             (lds_void*)&lbuf[c & 1][r * 64 + lane],
                                             16, 0, 0);
        }
    };

    float u = 0.f;
    int   cnt = 0;
    bool  sp1 = false, sp2 = false;

    stage(0);
    for (int c = 0; c < NCH; ++c) {
        if (c + 1 < NCH) {
            stage(c + 1);
            // Wait chunk c's 16 oldest DMAs; chunk c+1's 16 stay in flight
            // under this chunk's scan.
            asm volatile("s_waitcnt vmcnt(16)" ::: "memory");
        } else {
            asm volatile("s_waitcnt vmcnt(0)" ::: "memory");
        }
        __builtin_amdgcn_sched_barrier(0);

        // Whole chunk LDS -> registers up front (16 x ds_read_b128, compiler
        // pipelines lgkmcnt), then pin order so reads can't sink into the
        // serial chain. 64 VGPR live — no spill at 1 wave / launch_bounds(64).
        const float4* lb = lbuf[c & 1];
        float4 v[ROWS];
        #pragma unroll
        for (int r = 0; r < ROWS; ++r) v[r] = lb[r * 64 + lane];
        __builtin_amdgcn_sched_barrier(0);

        #pragma unroll
        for (int r = 0; r < ROWS; ++r) {
            LIF_STEP(v[r].x); LIF_STEP(v[r].y); LIF_STEP(v[r].z); LIF_STEP(v[r].w);
        }
    }

    // Epilogue: partial out_mean over this block's 64 neurons, atomic-combined.
    __syncthreads();
    cl[lane] = (float)cnt;
    __syncthreads();
    float a0 = 0.f, a1 = 0.f;
    #pragma unroll 8
    for (int k = 0; k < 64; ++k) {
        float c = cl[k];
        const float* w = hw + (size_t)(hbase + k) * O_DIM;
        a0 = fmaf(c, w[lane], a0);
        a1 = fmaf(c, w[lane + 64], a1);
    }
    a0 *= (1.0f / (float)S_LEN);
    a1 *= (1.0f / (float)S_LEN);
    for (int b = 0; b < B_SZ; ++b) {
        atomicAdd(out + b * O_DIM + lane,      a0);
        atomicAdd(out + b * O_DIM + lane + 64, a1);
    }
}

extern "C" void kernel_launch(void* const* d_in, const int* in_sizes, int n_in,
                              void* d_out, int out_size, void* d_ws, size_t ws_size,
                              hipStream_t stream) {
    const float4* x4 = (const float4*)d_in[0];       // [32,4096,512] f32
    const float*  iw = (const float*) d_in[1];       // [512,256] f32
    const float*  hw = (const float*) d_in[2];       // [256,128] f32
    float* out   = (float*)d_out;                    // [32,128] f32
    float4* cur4 = (float4*)d_ws;                    // [1024][256] float4 = 4 MB

    (void)hipMemsetAsync(out, 0, B_SZ * O_DIM * sizeof(float), stream);
    hipLaunchKernelGGL(snn_produce, dim3(NPROD), dim3(256), 0, stream,
                       x4, iw, cur4);
    hipLaunchKernelGGL(snn_scan, dim3(4), dim3(64), 0, stream,
                       cur4, hw, out);
}

// Round 8
// 467.544 us; speedup vs baseline: 1.0157x; 1.0016x over previous
//
#include <hip/hip_runtime.h>
#include <stdint.h>

// SpikingNeuralNetwork: B=32, S=4096, D=512, H=256, OUT=128
// TWO-KERNEL pipeline. Round-8 theory: the producer's batch-mean has been
// the hidden bottleneck all along (~150 us, 268 MB at only ~1.7 TB/s
// consumed). Its pattern: per wave, 8 interleaved 1KB segments strided 8 MB
// (32K live streams chip-wide, re-touched every ~900 cyc). This round makes
// the producer a LINEAR streamer per wave:
//
// Kernel A (snn_produce, 1024 blocks x 256): block f owns s-rows 4f..4f+3.
//   Per batch b, the contiguous 8 KB slab x[b, 4f:4f+4, :] is DMA'd with
//   global_load_lds (wave w covers bytes [w*2KB, (w+1)*2KB) as 2 x 1KB
//   back-to-back instructions -> consecutive instructions walk linearly)
//   into a 4-deep LDS ring slab[4][8KB]. Pipeline: prefetch 3 batches ahead
//   (~2700 cyc > HBM RTT); per iter: manual s_waitcnt vmcnt(4) (own 2 DMAs
//   for batch b retired), RAW s_barrier (NOT __syncthreads -- that emits
//   vmcnt(0) and drains the pipeline), issue batch b+3 (into the buffer
//   whose reads all retired before this barrier), read 2 float4 from LDS,
//   accumulate, asm lgkmcnt(0) (reads retired before next overwrite).
//   Accumulation per output slot is strictly ascending in b, one batch at a
//   time -- the IDENTICAL scalar-add sequence as the verified absmax-0.0
//   kernels (grouping in source differs; the per-slot op sequence does not).
//   Stage 2 GEMV + packed float4 store to cur4[f][h]: unchanged.
//   LDS 32+8 KB = 40 KB -> 4 blocks/CU -> 16 waves/CU.
// Kernel B (snn_scan, 4 blocks x 64): LIF scan, one neuron chain per lane.
//   3-buffer DMA ring, prefetch 2 chunks ahead: per chunk issue 16 x 16B
//   global_load_lds for chunk c+2, s_waitcnt vmcnt(32) (chunk c's 16
//   retired; c+1/c+2's 32 in flight -> DMA has ~2 chunk-times > RTT to
//   land), v[16] block copy, 64 serial LIF steps. Epilogue unchanged.
// Mean/GEMV/LIF/epilogue arithmetic bit-identical to rounds 0-7 (absmax 0.0).

#define S_LEN 4096
#define D_DIM 512
#define H_DIM 256
#define O_DIM 128
#define B_SZ  32

#define NPROD 1024              // producer blocks (4 s-rows each)
#define CH    64                // scan steps per chunk
#define NCH   (S_LEN / CH)      // 64 chunks
#define ROWS  (CH / 4)          // 16 float4-rows per chunk

typedef const __attribute__((address_space(1))) void  glob_void;
typedef       __attribute__((address_space(3))) void  lds_void;

// One LIF step, fused form (bit-exact to reference):
#define LIF_STEP(IC) {                          \
    float ict = sp2 ? 0.f : (IC);               \
    float tt  = fmaf(0.95f, u, ict);            \
    u   = sp1 ? 0.f : tt;                       \
    bool sp = (u >= 1.0f);                      \
    cnt += sp ? 1 : 0;                          \
    sp2 = sp1; sp1 = sp; }

#define ACC4(A, V) { A.x += V.x; A.y += V.y; A.z += V.z; A.w += V.w; }

__global__ __launch_bounds__(256)
void snn_produce(const float4* __restrict__ x4,
                 const float*  __restrict__ iw,
                 float4*       __restrict__ cur4) {   // packed [f][h], 4 MB
    __shared__ __attribute__((aligned(16))) float4 slab[4][512];  // 4 x 8 KB ring
    __shared__ float4 xm[512];               // 4 s-rows x 512 f32 = 8 KB
    const int t    = threadIdx.x;
    const int w    = t >> 6;                 // wave 0..3
    const int lane = t & 63;
    const int r2   = t >> 7;                 // 0..1: this thread's row pair
    const int d4   = t & 127;
    const int h    = t;
    const float inv = 1.0f / (float)B_SZ;
    const size_t bstr = (size_t)S_LEN * (D_DIM / 4);   // batch stride (float4)

    const int f = (int)blockIdx.x;           // float4-row 0..1023
    // Contiguous 8 KB slab base for batch b: x[b, 4f:4f+4, :].
    const float4* sbase = x4 + (size_t)(4 * f) * (D_DIM / 4);

    // Wave w DMAs bytes [w*2KB, (w+1)*2KB) of batch-b's slab: two 1KB-
    // contiguous instructions (dst = uniform base + lane*16 -> layout OK).
    auto issue = [&](int b) {
        const float4* g = sbase + (size_t)b * bstr + w * 128 + lane;
        __builtin_amdgcn_global_load_lds((glob_void*)g,
                                         (lds_void*)&slab[b & 3][w * 128 + lane],
                                         16, 0, 0);
        __builtin_amdgcn_global_load_lds((glob_void*)(g + 64),
                                         (lds_void*)&slab[b & 3][w * 128 + 64 + lane],
                                         16, 0, 0);
    };

    issue(0); issue(1); issue(2);            // prefetch depth 3

    float4 a0 = make_float4(0.f, 0.f, 0.f, 0.f);
    float4 a1 = make_float4(0.f, 0.f, 0.f, 0.f);
    for (int b = 0; b < B_SZ; ++b) {
        // Own DMAs for batch b retired (2 per batch in flight beyond b).
        if (b < B_SZ - 2)      asm volatile("s_waitcnt vmcnt(4)" ::: "memory");
        else if (b == B_SZ - 2) asm volatile("s_waitcnt vmcnt(2)" ::: "memory");
        else                    asm volatile("s_waitcnt vmcnt(0)" ::: "memory");
        // RAW barrier: all waves' DMA-waits done -> slab b complete in LDS.
        // (__syncthreads would emit vmcnt(0) and drain the whole pipeline.)
        __builtin_amdgcn_s_barrier();
        __builtin_amdgcn_sched_barrier(0);
        // Refill: buffer (b+3)&3 == (b-1)&3; every wave's reads of batch b-1
        // retired before this barrier (lgkmcnt(0) at end of prior iter).
        if (b + 3 < B_SZ) issue(b + 3);
        // Accumulate batch b: per output slot ascending-b scalar adds,
        // identical op sequence to the verified kernels.
        float4 v0 = slab[b & 3][r2 * 128 + d4];          // row r2
        float4 v1 = slab[b & 3][(r2 + 2) * 128 + d4];    // row r2+2
        ACC4(a0, v0);
        ACC4(a1, v1);
        asm volatile("s_waitcnt lgkmcnt(0)" ::: "memory");  // reads retired
        __builtin_amdgcn_sched_barrier(0);
    }

    a0.x *= inv; a0.y *= inv; a0.z *= inv; a0.w *= inv;
    a1.x *= inv; a1.y *= inv; a1.z *= inv; a1.w *= inv;
    xm[r2 * 128 + d4]       = a0;            // row r2
    xm[(r2 + 2) * 128 + d4] = a1;            // row r2+2
    __syncthreads();                         // pipeline drained (vmcnt==0)

    // Stage 2: currents[4f+r][h] = sum_d xm[r][d] * W_in[d][h]; thread = h.
    float acc2[4] = {0.f, 0.f, 0.f, 0.f};
    for (int d4i = 0; d4i < D_DIM / 4; ++d4i) {
        const int d = d4i * 4;
        float w0 = iw[(d + 0) * H_DIM + h];
        float w1 = iw[(d + 1) * H_DIM + h];
        float w2 = iw[(d + 2) * H_DIM + h];
        float w3 = iw[(d + 3) * H_DIM + h];
        #pragma unroll
        for (int r = 0; r < 4; ++r) {
            float4 xv = xm[r * 128 + d4i];   // same-addr broadcast: free
            acc2[r] += xv.x * w0 + xv.y * w1 + xv.z * w2 + xv.w * w3;
        }
    }
    // Packed coalesced store: lane h contiguous -> 16 B/lane, full lines.
    cur4[(size_t)f * H_DIM + h] = make_float4(acc2[0], acc2[1], acc2[2], acc2[3]);
}

__global__ __launch_bounds__(64)
void snn_scan(const float4* __restrict__ cur4,
              const float*  __restrict__ hw,
              float*        __restrict__ out) {
    __shared__ __attribute__((aligned(16))) float4 lbuf[3][ROWS * 64];  // 3x16KB
    __shared__ float cl[64];
    const int lane  = threadIdx.x;           // one neuron chain per lane
    const int hbase = (int)blockIdx.x * 64;  // 4 blocks cover h=0..255

    // 16 x 16B DMA for chunk c into ring buffer idx.
    auto stage = [&](int c, int idx) {
        #pragma unroll
        for (int r = 0; r < ROWS; ++r) {
            const float4* g = cur4 + (size_t)(c * ROWS + r) * H_DIM + hbase + lane;
            __builtin_amdgcn_global_load_lds((glob_void*)g,
                                             (lds_void*)&lbuf[idx][r * 64 + lane],
                                             16, 0, 0);
        }
    };

    float u = 0.f;
    int   cnt = 0;
    bool  sp1 = false, sp2 = false;

    stage(0, 0);
    stage(1, 1);
    int rd = 0, st = 2;                      // ring read / stage cursors
    for (int c = 0; c < NCH; ++c) {
        if (c + 2 < NCH) {
            stage(c + 2, st);
            st = (st == 2) ? 0 : st + 1;
            // Chunk c's 16 oldest retired; c+1/c+2's 32 stay in flight
            // (issued ~2 chunk-times ago -> HBM/L3 RTT fully covered).
            asm volatile("s_waitcnt vmcnt(32)" ::: "memory");
        } else if (c + 1 < NCH) {
            asm volatile("s_waitcnt vmcnt(16)" ::: "memory");
        } else {
            asm volatile("s_waitcnt vmcnt(0)" ::: "memory");
        }
        __builtin_amdgcn_sched_barrier(0);

        // Whole chunk LDS -> registers up front (16 x ds_read_b128), then pin
        // order so reads can't sink into the serial chain.
        const float4* lb = &lbuf[rd][0];
        rd = (rd == 2) ? 0 : rd + 1;
        float4 v[ROWS];
        #pragma unroll
        for (int r = 0; r < ROWS; ++r) v[r] = lb[r * 64 + lane];
        __builtin_amdgcn_sched_barrier(0);

        #pragma unroll
        for (int r = 0; r < ROWS; ++r) {
            LIF_STEP(v[r].x); LIF_STEP(v[r].y); LIF_STEP(v[r].z); LIF_STEP(v[r].w);
        }
    }

    // Epilogue: partial out_mean over this block's 64 neurons, atomic-combined.
    __syncthreads();
    cl[lane] = (float)cnt;
    __syncthreads();
    float a0 = 0.f, a1 = 0.f;
    #pragma unroll 8
    for (int k = 0; k < 64; ++k) {
        float c = cl[k];
        const float* w = hw + (size_t)(hbase + k) * O_DIM;
        a0 = fmaf(c, w[lane], a0);
        a1 = fmaf(c, w[lane + 64], a1);
    }
    a0 *= (1.0f / (float)S_LEN);
    a1 *= (1.0f / (float)S_LEN);
    for (int b = 0; b < B_SZ; ++b) {
        atomicAdd(out + b * O_DIM + lane,      a0);
        atomicAdd(out + b * O_DIM + lane + 64, a1);
    }
}

extern "C" void kernel_launch(void* const* d_in, const int* in_sizes, int n_in,
                              void* d_out, int out_size, void* d_ws, size_t ws_size,
                              hipStream_t stream) {
    const float4* x4 = (const float4*)d_in[0];       // [32,4096,512] f32
    const float*  iw = (const float*) d_in[1];       // [512,256] f32
    const float*  hw = (const float*) d_in[2];       // [256,128] f32
    float* out   = (float*)d_out;                    // [32,128] f32
    float4* cur4 = (float4*)d_ws;                    // [1024][256] float4 = 4 MB

    (void)hipMemsetAsync(out, 0, B_SZ * O_DIM * sizeof(float), stream);
    hipLaunchKernelGGL(snn_produce, dim3(NPROD), dim3(256), 0, stream,
                       x4, iw, cur4);
    hipLaunchKernelGGL(snn_scan, dim3(4), dim3(64), 0, stream,
                       cur4, hw, out);
}